// Round 2
// baseline (1373.660 us; speedup 1.0000x reference)
//
#include <hip/hip_runtime.h>
#include <math.h>

#define BB   16
#define NN   2048
#define DIN  512
#define DKK  10
#define NHD  2
#define DH   5
#define HID  20
#define DOUT 512
#define BH   32          // BB*NHD
#define KC   256         // attention k-chunk
#define NKC  8           // NN/KC

// ws layout (floats):
//   qkv  : [3][BH][NN][8]   (q pre-scaled by 1/sqrt(5); rows padded 5->8)
//   part : [NKC][BH][NN][8] (acc[0..4], denom at [5])
//   Wpack: [512][32]        (Wq|Wk|Wv rows packed+padded, 128B-aligned rows)
#define QKV_ELEMS  ((size_t)3*BH*NN*8)
#define PART_ELEMS ((size_t)NKC*BH*NN*8)

// ---------------------------------------------------------------- kernel 0
// Pack Wq|Wk|Wv into [512][32] rows (cols 0-9 q, 10-19 k, 20-29 v, 30-31 zero)
__global__ __launch_bounds__(256) void pack_w_kernel(
    const float* __restrict__ Wq, const float* __restrict__ Wk,
    const float* __restrict__ Wv, float* __restrict__ Wpack)
{
    const int idx = blockIdx.x*256 + threadIdx.x;   // 0..16383
    const int j = idx >> 5, c = idx & 31;
    float v = 0.f;
    if (c < 10)      v = Wq[j*DKK + c];
    else if (c < 20) v = Wk[j*DKK + (c-10)];
    else if (c < 30) v = Wv[j*DKK + (c-20)];
    Wpack[idx] = v;
}

// ---------------------------------------------------------------- kernel 1
// block = 512 (8 waves). lane = token (64 tokens/block), wave = 64-dim k-chunk.
// W rows come in as broadcast float4 vector loads (VGPR operands, no SGPR
// staging); partials reduced via padded LDS. 512 blocks -> 4096 waves.
__global__ __launch_bounds__(512, 4) void proj_kernel(
    const float* __restrict__ x, const float* __restrict__ Wpack,
    const float* __restrict__ bq, const float* __restrict__ bk,
    const float* __restrict__ bv, float* __restrict__ qkv)
{
    __shared__ float red[8*64*33];                 // 67.6 KB, +1 pad: no conflicts
    const int lane = threadIdx.x & 63;
    const int w    = threadIdx.x >> 6;             // k-chunk 0..7
    const int tok  = blockIdx.x*64 + lane;

    const float* xr = x + (size_t)tok*DIN + w*64;
    const float* wp = Wpack + (size_t)w*64*32;

    float acc[32];
    #pragma unroll
    for (int o=0;o<32;o++) acc[o]=0.f;

    float4 xa0,xa1,xa2,xa3;
    xa0 = *(const float4*)(xr+ 0); xa1 = *(const float4*)(xr+ 4);
    xa2 = *(const float4*)(xr+ 8); xa3 = *(const float4*)(xr+12);

    for (int c=0;c<4;c++){
        float4 xb0,xb1,xb2,xb3;
        if (c<3){
            const float* p = xr + (c+1)*16;        // prefetch next 64B line
            xb0=*(const float4*)(p+ 0); xb1=*(const float4*)(p+ 4);
            xb2=*(const float4*)(p+ 8); xb3=*(const float4*)(p+12);
        }
        const float xs[16] = {xa0.x,xa0.y,xa0.z,xa0.w, xa1.x,xa1.y,xa1.z,xa1.w,
                              xa2.x,xa2.y,xa2.z,xa2.w, xa3.x,xa3.y,xa3.z,xa3.w};
        #pragma unroll
        for (int t=0;t<16;t++){
            const float xj = xs[t];
            const float4* wrow = (const float4*)(wp + (size_t)(c*16+t)*32);
            #pragma unroll
            for (int r=0;r<8;r++){
                const float4 wv = wrow[r];         // wave-uniform -> broadcast
                acc[r*4+0] = fmaf(xj, wv.x, acc[r*4+0]);
                acc[r*4+1] = fmaf(xj, wv.y, acc[r*4+1]);
                acc[r*4+2] = fmaf(xj, wv.z, acc[r*4+2]);
                acc[r*4+3] = fmaf(xj, wv.w, acc[r*4+3]);
            }
        }
        if (c<3){ xa0=xb0; xa1=xb1; xa2=xb2; xa3=xb3; }
    }

    float* myred = red + (size_t)(w*64 + lane)*33;
    #pragma unroll
    for (int o=0;o<30;o++) myred[o] = acc[o];
    __syncthreads();

    const float qs = 0.44721359549995793f;         // 1/sqrt(5) folded into Q
    for (int idx = threadIdx.x; idx < 64*30; idx += 512){
        const int tl = idx / 30;
        const int o  = idx - tl*30;
        float s = 0.f;
        #pragma unroll
        for (int ww=0; ww<8; ww++) s += red[(size_t)(ww*64+tl)*33 + o];
        const int mat = o / 10;                    // 0=q 1=k 2=v
        const int d10 = o - mat*10;
        const int h   = d10 / 5;
        const int dd  = d10 - h*5;
        const float bias = (mat==0) ? bq[d10] : (mat==1) ? bk[d10] : bv[d10];
        s += bias;
        if (mat==0) s *= qs;
        const int t2 = blockIdx.x*64 + tl;
        const int b  = t2 >> 11;
        const int n  = t2 & (NN-1);
        qkv[(size_t)mat*BH*NN*8 + (((size_t)(b*NHD+h))*NN + n)*8 + dd] = s;
    }
}

// ---------------------------------------------------------------- kernel 2
// grid (qt=32, kc=8, bh=32), block 64. One q-row per lane, wave-uniform k.
// scores = sin(q.k/sqrt5) are in [-1,1] -> exp(sin) needs no max pass.
__global__ __launch_bounds__(64) void attn_kernel(
    const float* __restrict__ qkv, float* __restrict__ part)
{
    const int qt   = blockIdx.x;
    const int kc   = blockIdx.y;
    const int bh   = blockIdx.z;
    const int lane = threadIdx.x;
    const int qtile0 = qt*64;
    const int k0     = kc*KC;
    if (k0 > qtile0 + 63) return;          // uniform early-out (causal)

    const int q = qtile0 + lane;
    const float* qr = qkv + ((size_t)bh*NN + q)*8;
    const float4 qv = *(const float4*)qr;
    const float  q4 = qr[4];

    const float* kbase = qkv + (size_t)BH*NN*8 + (size_t)bh*NN*8;
    const float* vbase = kbase + (size_t)BH*NN*8;
    const int kend = (k0+KC < qtile0+64) ? (k0+KC) : (qtile0+64);  // uniform

    float denom=0.f, a0=0.f, a1=0.f, a2=0.f, a3=0.f, a4=0.f;
    #pragma unroll 4
    for (int k=k0; k<kend; ++k){
        const float* kr = kbase + (size_t)k*8;   // wave-uniform
        const float* vr = vbase + (size_t)k*8;
        float s = qv.x*kr[0] + qv.y*kr[1] + qv.z*kr[2] + qv.w*kr[3] + q4*kr[4];
        float e = __expf(__sinf(s));
        e = (k <= q) ? e : 0.f;                  // causal mask, per-lane
        denom += e;
        a0 = fmaf(e, vr[0], a0);
        a1 = fmaf(e, vr[1], a1);
        a2 = fmaf(e, vr[2], a2);
        a3 = fmaf(e, vr[3], a3);
        a4 = fmaf(e, vr[4], a4);
    }
    float* pr = part + (((size_t)kc*BH + bh)*NN + q)*8;
    *(float4*)pr = make_float4(a0,a1,a2,a3);
    pr[4] = a4;
    pr[5] = denom;
}

// ---------------------------------------------------------------- kernel 3
// One wave handles half an output row (256 cols, 4 per lane) for 8 tokens;
// Wm2 column-slice lives in registers, stores are coalesced dwordx4.
__global__ __launch_bounds__(256) void mlp_kernel(
    const float* __restrict__ part,
    const float* __restrict__ Wm1, const float* __restrict__ bm1,
    const float* __restrict__ Wm2, const float* __restrict__ bm2,
    float* __restrict__ out)
{
    const int wave = threadIdx.x >> 6;
    const int lane = threadIdx.x & 63;
    const int unit = blockIdx.x*4 + wave;   // 0..8191
    const int hc   = unit & 1;              // which half of the 512 outputs
    const int tg   = unit >> 1;             // token group of 8
    const int o0   = hc*256 + lane*4;

    float4 w2[HID];
    #pragma unroll
    for (int j=0;j<HID;j++) w2[j] = *(const float4*)(Wm2 + j*DOUT + o0);
    const float4 b2 = *(const float4*)(bm2 + o0);

    for (int ti=0; ti<8; ++ti){
        const int tok = tg*8 + ti;
        const int b   = tok >> 11;
        const int n   = tok & (NN-1);

        float vals[DKK];
        #pragma unroll
        for (int h=0;h<NHD;h++){
            const int bh = b*NHD + h;
            float s0=0,s1=0,s2=0,s3=0,s4=0,sd=0;
            const int nc = (n >> 8) + 1;    // valid causal k-chunks
            for (int c=0;c<nc;c++){
                const float* pr = part + (((size_t)c*BH + bh)*NN + n)*8;  // uniform
                s0+=pr[0]; s1+=pr[1]; s2+=pr[2]; s3+=pr[3]; s4+=pr[4]; sd+=pr[5];
            }
            const float inv = 1.0f / sd;
            vals[h*DH+0]=s0*inv; vals[h*DH+1]=s1*inv; vals[h*DH+2]=s2*inv;
            vals[h*DH+3]=s3*inv; vals[h*DH+4]=s4*inv;
        }

        float h1[HID];
        #pragma unroll
        for (int jo=0;jo<HID;jo++){
            float t = bm1[jo];
            #pragma unroll
            for (int d=0;d<DKK;d++) t = fmaf(vals[d], Wm1[d*HID+jo], t);
            h1[jo] = (t > 0.f) ? t : 0.01f*t;   // leaky_relu
        }

        float4 acc = b2;
        #pragma unroll
        for (int j=0;j<HID;j++){
            acc.x = fmaf(h1[j], w2[j].x, acc.x);
            acc.y = fmaf(h1[j], w2[j].y, acc.y);
            acc.z = fmaf(h1[j], w2[j].z, acc.z);
            acc.w = fmaf(h1[j], w2[j].w, acc.w);
        }
        *(float4*)(out + (size_t)tok*DOUT + o0) = acc;
    }
}

// ---------------------------------------------------------------- launch
extern "C" void kernel_launch(void* const* d_in, const int* in_sizes, int n_in,
                              void* d_out, int out_size, void* d_ws, size_t ws_size,
                              hipStream_t stream) {
    const float* x   = (const float*)d_in[0];
    const float* Wq  = (const float*)d_in[1];
    const float* bq  = (const float*)d_in[2];
    const float* Wk  = (const float*)d_in[3];
    const float* bk  = (const float*)d_in[4];
    const float* Wv  = (const float*)d_in[5];
    const float* bv  = (const float*)d_in[6];
    const float* Wm1 = (const float*)d_in[7];
    const float* bm1 = (const float*)d_in[8];
    const float* Wm2 = (const float*)d_in[9];
    const float* bm2 = (const float*)d_in[10];
    float* out = (float*)d_out;

    float* qkv   = (float*)d_ws;
    float* part  = qkv + QKV_ELEMS;
    float* Wpack = part + PART_ELEMS;
    // every part[]/qkv[] slot later kernels read is written each call:
    // no memset needed, re-poison safe.

    pack_w_kernel<<<dim3(64), dim3(256), 0, stream>>>(Wq, Wk, Wv, Wpack);
    proj_kernel<<<dim3(512), dim3(512), 0, stream>>>(x, Wpack, bq, bk, bv, qkv);
    attn_kernel<<<dim3(32, NKC, BH), dim3(64), 0, stream>>>(qkv, part);
    mlp_kernel<<<dim3(2048), dim3(256), 0, stream>>>(part, Wm1,bm1, Wm2,bm2, out);
}

// Round 3
// 451.386 us; speedup vs baseline: 3.0432x; 3.0432x over previous
//
#include <hip/hip_runtime.h>
#include <math.h>

#define BB   16
#define NN   2048
#define DIN  512
#define DKK  10
#define NHD  2
#define DH   5
#define HID  20
#define DOUT 512
#define BH   32          // BB*NHD
#define KC   256         // attention k-chunk
#define NKC  8           // NN/KC
#define CK   128         // proj k-chunk staged in LDS
#define XSTR 132         // padded x-tile stride (floats)

// ws layout (floats):
//   qkv  : [3][BH][NN][8]   (q pre-scaled by 1/sqrt(5); rows padded 5->8)
//   part : [NKC][BH][NN][8] (acc[0..4], denom at [5])
//   Wpack: [512][32]        (Wq|Wk|Wv rows packed+padded, 128B-aligned rows)
#define QKV_ELEMS  ((size_t)3*BH*NN*8)
#define PART_ELEMS ((size_t)NKC*BH*NN*8)

// ---------------------------------------------------------------- kernel 0
// Pack Wq|Wk|Wv into [512][32] rows (cols 0-9 q, 10-19 k, 20-29 v, 30-31 zero)
__global__ __launch_bounds__(256) void pack_w_kernel(
    const float* __restrict__ Wq, const float* __restrict__ Wk,
    const float* __restrict__ Wv, float* __restrict__ Wpack)
{
    const int idx = blockIdx.x*256 + threadIdx.x;   // 0..16383
    const int j = idx >> 5, c = idx & 31;
    float v = 0.f;
    if (c < 10)      v = Wq[j*DKK + c];
    else if (c < 20) v = Wk[j*DKK + (c-10)];
    else if (c < 30) v = Wv[j*DKK + (c-20)];
    Wpack[idx] = v;
}

// ---------------------------------------------------------------- kernel 1
// block = 256 threads = 32 tokens x 8 out-groups. Each thread: acc = float4
// (packed cols 4r..4r+3) -> ~40 VGPR, no spill (R2's 64-VGPR cap spilled
// acc[32] -> 2.9 GB scratch traffic; this structure cannot spill).
// x tile + W chunk staged in LDS; W reads are wave-uniform broadcasts.
__global__ __launch_bounds__(256) void proj_kernel(
    const float* __restrict__ x, const float* __restrict__ Wpack,
    const float* __restrict__ bq, const float* __restrict__ bk,
    const float* __restrict__ bv, float* __restrict__ qkv)
{
    __shared__ float xs[32*XSTR];   // 16.9 KB
    __shared__ float ws[CK*32];     // 16 KB
    const int t  = threadIdx.x;
    const int tl = t & 31;          // token-local 0..31
    const int r  = t >> 5;          // out-group 0..7
    const int tok0 = blockIdx.x * 32;

    float4 acc = make_float4(0.f, 0.f, 0.f, 0.f);

    for (int ch = 0; ch < DIN/CK; ++ch){
        __syncthreads();
        // stage x tile: 32 tokens x 128 dims = 1024 float4, 4 per thread
        #pragma unroll
        for (int i=0;i<4;i++){
            const int f = t + i*256;
            const int xtok = f >> 5, c4 = f & 31;   // 32 float4 per row
            const float4 v = *(const float4*)(x + (size_t)(tok0+xtok)*DIN + ch*CK + c4*4);
            *(float4*)(xs + xtok*XSTR + c4*4) = v;
        }
        // stage W chunk: 128 rows x 32 cols = 1024 float4, 4 per thread
        #pragma unroll
        for (int i=0;i<4;i++){
            const int f = t + i*256;
            const int row = f >> 3, c4 = f & 7;     // 8 float4 per row
            const float4 v = *(const float4*)(Wpack + (size_t)(ch*CK+row)*32 + c4*4);
            *(float4*)(ws + row*32 + c4*4) = v;
        }
        __syncthreads();

        #pragma unroll 8
        for (int kk = 0; kk < CK; kk += 4){
            const float4 xv = *(const float4*)(xs + tl*XSTR + kk);
            const float4 w0 = *(const float4*)(ws + (kk+0)*32 + r*4);  // broadcast
            const float4 w1 = *(const float4*)(ws + (kk+1)*32 + r*4);
            const float4 w2 = *(const float4*)(ws + (kk+2)*32 + r*4);
            const float4 w3 = *(const float4*)(ws + (kk+3)*32 + r*4);
            acc.x = fmaf(xv.x, w0.x, acc.x);
            acc.y = fmaf(xv.x, w0.y, acc.y);
            acc.z = fmaf(xv.x, w0.z, acc.z);
            acc.w = fmaf(xv.x, w0.w, acc.w);
            acc.x = fmaf(xv.y, w1.x, acc.x);
            acc.y = fmaf(xv.y, w1.y, acc.y);
            acc.z = fmaf(xv.y, w1.z, acc.z);
            acc.w = fmaf(xv.y, w1.w, acc.w);
            acc.x = fmaf(xv.z, w2.x, acc.x);
            acc.y = fmaf(xv.z, w2.y, acc.y);
            acc.z = fmaf(xv.z, w2.z, acc.z);
            acc.w = fmaf(xv.z, w2.w, acc.w);
            acc.x = fmaf(xv.w, w3.x, acc.x);
            acc.y = fmaf(xv.w, w3.y, acc.y);
            acc.z = fmaf(xv.w, w3.z, acc.z);
            acc.w = fmaf(xv.w, w3.w, acc.w);
        }
    }

    // epilogue: packed col c = 4r+i -> (mat, head, dim); add bias, scale q
    const float qs = 0.44721359549995793f;          // 1/sqrt(5)
    const int tok = tok0 + tl;
    const int b   = tok >> 11;
    const int n   = tok & (NN-1);
    const float av[4] = {acc.x, acc.y, acc.z, acc.w};
    #pragma unroll
    for (int i=0;i<4;i++){
        const int c = r*4 + i;
        if (c >= 30) continue;
        const int mat = c / 10;
        const int d10 = c - mat*10;
        const int h   = d10 / 5;
        const int dd  = d10 - h*5;
        float v = av[i] + ((mat==0) ? bq[d10] : (mat==1) ? bk[d10] : bv[d10]);
        if (mat==0) v *= qs;
        qkv[(size_t)mat*BH*NN*8 + (((size_t)(b*NHD+h))*NN + n)*8 + dd] = v;
    }
}

// ---------------------------------------------------------------- kernel 2
// grid (qt=32, kc=8, bh=32), block 64. One q-row per lane, wave-uniform k.
// scores = sin(q.k/sqrt5) are in [-1,1] -> exp(sin) needs no max pass.
__global__ __launch_bounds__(64) void attn_kernel(
    const float* __restrict__ qkv, float* __restrict__ part)
{
    const int qt   = blockIdx.x;
    const int kc   = blockIdx.y;
    const int bh   = blockIdx.z;
    const int lane = threadIdx.x;
    const int qtile0 = qt*64;
    const int k0     = kc*KC;
    if (k0 > qtile0 + 63) return;          // uniform early-out (causal)

    const int q = qtile0 + lane;
    const float* qr = qkv + ((size_t)bh*NN + q)*8;
    const float4 qv = *(const float4*)qr;
    const float  q4 = qr[4];

    const float* kbase = qkv + (size_t)BH*NN*8 + (size_t)bh*NN*8;
    const float* vbase = kbase + (size_t)BH*NN*8;
    const int kend = (k0+KC < qtile0+64) ? (k0+KC) : (qtile0+64);  // uniform

    float denom=0.f, a0=0.f, a1=0.f, a2=0.f, a3=0.f, a4=0.f;
    #pragma unroll 4
    for (int k=k0; k<kend; ++k){
        const float* kr = kbase + (size_t)k*8;   // wave-uniform
        const float* vr = vbase + (size_t)k*8;
        float s = qv.x*kr[0] + qv.y*kr[1] + qv.z*kr[2] + qv.w*kr[3] + q4*kr[4];
        float e = __expf(__sinf(s));
        e = (k <= q) ? e : 0.f;                  // causal mask, per-lane
        denom += e;
        a0 = fmaf(e, vr[0], a0);
        a1 = fmaf(e, vr[1], a1);
        a2 = fmaf(e, vr[2], a2);
        a3 = fmaf(e, vr[3], a3);
        a4 = fmaf(e, vr[4], a4);
    }
    float* pr = part + (((size_t)kc*BH + bh)*NN + q)*8;
    *(float4*)pr = make_float4(a0,a1,a2,a3);
    pr[4] = a4;
    pr[5] = denom;
}

// ---------------------------------------------------------------- kernel 3
// One wave handles half an output row (256 cols, 4 per lane) for 8 tokens;
// Wm2 column-slice lives in registers, stores are coalesced dwordx4.
__global__ __launch_bounds__(256) void mlp_kernel(
    const float* __restrict__ part,
    const float* __restrict__ Wm1, const float* __restrict__ bm1,
    const float* __restrict__ Wm2, const float* __restrict__ bm2,
    float* __restrict__ out)
{
    const int wave = threadIdx.x >> 6;
    const int lane = threadIdx.x & 63;
    const int unit = blockIdx.x*4 + wave;   // 0..8191
    const int hc   = unit & 1;              // which half of the 512 outputs
    const int tg   = unit >> 1;             // token group of 8
    const int o0   = hc*256 + lane*4;

    float4 w2[HID];
    #pragma unroll
    for (int j=0;j<HID;j++) w2[j] = *(const float4*)(Wm2 + j*DOUT + o0);
    const float4 b2 = *(const float4*)(bm2 + o0);

    for (int ti=0; ti<8; ++ti){
        const int tok = tg*8 + ti;
        const int b   = tok >> 11;
        const int n   = tok & (NN-1);

        float vals[DKK];
        #pragma unroll
        for (int h=0;h<NHD;h++){
            const int bh = b*NHD + h;
            float s0=0,s1=0,s2=0,s3=0,s4=0,sd=0;
            const int nc = (n >> 8) + 1;    // valid causal k-chunks
            for (int c=0;c<nc;c++){
                const float* pr = part + (((size_t)c*BH + bh)*NN + n)*8;  // uniform
                s0+=pr[0]; s1+=pr[1]; s2+=pr[2]; s3+=pr[3]; s4+=pr[4]; sd+=pr[5];
            }
            const float inv = 1.0f / sd;
            vals[h*DH+0]=s0*inv; vals[h*DH+1]=s1*inv; vals[h*DH+2]=s2*inv;
            vals[h*DH+3]=s3*inv; vals[h*DH+4]=s4*inv;
        }

        float h1[HID];
        #pragma unroll
        for (int jo=0;jo<HID;jo++){
            float t = bm1[jo];
            #pragma unroll
            for (int d=0;d<DKK;d++) t = fmaf(vals[d], Wm1[d*HID+jo], t);
            h1[jo] = (t > 0.f) ? t : 0.01f*t;   // leaky_relu
        }

        float4 acc = b2;
        #pragma unroll
        for (int j=0;j<HID;j++){
            acc.x = fmaf(h1[j], w2[j].x, acc.x);
            acc.y = fmaf(h1[j], w2[j].y, acc.y);
            acc.z = fmaf(h1[j], w2[j].z, acc.z);
            acc.w = fmaf(h1[j], w2[j].w, acc.w);
        }
        *(float4*)(out + (size_t)tok*DOUT + o0) = acc;
    }
}

// ---------------------------------------------------------------- launch
extern "C" void kernel_launch(void* const* d_in, const int* in_sizes, int n_in,
                              void* d_out, int out_size, void* d_ws, size_t ws_size,
                              hipStream_t stream) {
    const float* x   = (const float*)d_in[0];
    const float* Wq  = (const float*)d_in[1];
    const float* bq  = (const float*)d_in[2];
    const float* Wk  = (const float*)d_in[3];
    const float* bk  = (const float*)d_in[4];
    const float* Wv  = (const float*)d_in[5];
    const float* bv  = (const float*)d_in[6];
    const float* Wm1 = (const float*)d_in[7];
    const float* bm1 = (const float*)d_in[8];
    const float* Wm2 = (const float*)d_in[9];
    const float* bm2 = (const float*)d_in[10];
    float* out = (float*)d_out;

    float* qkv   = (float*)d_ws;
    float* part  = qkv + QKV_ELEMS;
    float* Wpack = part + PART_ELEMS;
    // every part[]/qkv[] slot later kernels read is written each call:
    // no memset needed, re-poison safe.

    pack_w_kernel<<<dim3(64), dim3(256), 0, stream>>>(Wq, Wk, Wv, Wpack);
    proj_kernel<<<dim3(1024), dim3(256), 0, stream>>>(x, Wpack, bq, bk, bv, qkv);
    attn_kernel<<<dim3(32, NKC, BH), dim3(64), 0, stream>>>(qkv, part);
    mlp_kernel<<<dim3(2048), dim3(256), 0, stream>>>(part, Wm1,bm1, Wm2,bm2, out);
}

// Round 4
// 292.945 us; speedup vs baseline: 4.6891x; 1.5409x over previous
//
#include <hip/hip_runtime.h>
#include <math.h>

#define BB   16
#define NN   2048
#define DIN  512
#define DKK  10
#define NHD  2
#define DH   5
#define HID  20
#define DOUT 512
#define BH   32          // BB*NHD
#define KC   256         // attention k-chunk
#define NKC  8           // NN/KC
#define CK   128         // proj k-chunk staged in LDS
#define XSTR 132         // padded x-tile stride (floats)

// ws layout (floats):
//   qkv  : [3][BH][NN][8]   (q pre-scaled by 1/sqrt(5); rows padded 5->8)
//   part : [NKC][BH][NN][8] (acc[0..4], denom at [5])
//   Wpack: [512][32]        (Wq|Wk|Wv rows packed+padded, 128B-aligned rows)
//   h1   : [B*N][20]        overlays qkv (dead after attn) -> no ws growth
#define QKV_ELEMS  ((size_t)3*BH*NN*8)
#define PART_ELEMS ((size_t)NKC*BH*NN*8)

// ---------------------------------------------------------------- kernel 0
// Pack Wq|Wk|Wv into [512][32] rows (cols 0-9 q, 10-19 k, 20-29 v, 30-31 zero)
__global__ __launch_bounds__(256) void pack_w_kernel(
    const float* __restrict__ Wq, const float* __restrict__ Wk,
    const float* __restrict__ Wv, float* __restrict__ Wpack)
{
    const int idx = blockIdx.x*256 + threadIdx.x;   // 0..16383
    const int j = idx >> 5, c = idx & 31;
    float v = 0.f;
    if (c < 10)      v = Wq[j*DKK + c];
    else if (c < 20) v = Wk[j*DKK + (c-10)];
    else if (c < 30) v = Wv[j*DKK + (c-20)];
    Wpack[idx] = v;
}

// ---------------------------------------------------------------- kernel 1
// block = 256 threads = 32 tokens x 8 out-groups. Each thread: acc = float4.
// x tile + W chunk staged in LDS; W reads are wave-uniform broadcasts.
__global__ __launch_bounds__(256) void proj_kernel(
    const float* __restrict__ x, const float* __restrict__ Wpack,
    const float* __restrict__ bq, const float* __restrict__ bk,
    const float* __restrict__ bv, float* __restrict__ qkv)
{
    __shared__ float xs[32*XSTR];   // 16.9 KB
    __shared__ float ws[CK*32];     // 16 KB
    const int t  = threadIdx.x;
    const int tl = t & 31;          // token-local 0..31
    const int r  = t >> 5;          // out-group 0..7
    const int tok0 = blockIdx.x * 32;

    float4 acc = make_float4(0.f, 0.f, 0.f, 0.f);

    for (int ch = 0; ch < DIN/CK; ++ch){
        __syncthreads();
        #pragma unroll
        for (int i=0;i<4;i++){
            const int f = t + i*256;
            const int xtok = f >> 5, c4 = f & 31;
            const float4 v = *(const float4*)(x + (size_t)(tok0+xtok)*DIN + ch*CK + c4*4);
            *(float4*)(xs + xtok*XSTR + c4*4) = v;
        }
        #pragma unroll
        for (int i=0;i<4;i++){
            const int f = t + i*256;
            const int row = f >> 3, c4 = f & 7;
            const float4 v = *(const float4*)(Wpack + (size_t)(ch*CK+row)*32 + c4*4);
            *(float4*)(ws + row*32 + c4*4) = v;
        }
        __syncthreads();

        #pragma unroll 8
        for (int kk = 0; kk < CK; kk += 4){
            const float4 xv = *(const float4*)(xs + tl*XSTR + kk);
            const float4 w0 = *(const float4*)(ws + (kk+0)*32 + r*4);
            const float4 w1 = *(const float4*)(ws + (kk+1)*32 + r*4);
            const float4 w2 = *(const float4*)(ws + (kk+2)*32 + r*4);
            const float4 w3 = *(const float4*)(ws + (kk+3)*32 + r*4);
            acc.x = fmaf(xv.x, w0.x, acc.x);
            acc.y = fmaf(xv.x, w0.y, acc.y);
            acc.z = fmaf(xv.x, w0.z, acc.z);
            acc.w = fmaf(xv.x, w0.w, acc.w);
            acc.x = fmaf(xv.y, w1.x, acc.x);
            acc.y = fmaf(xv.y, w1.y, acc.y);
            acc.z = fmaf(xv.y, w1.z, acc.z);
            acc.w = fmaf(xv.y, w1.w, acc.w);
            acc.x = fmaf(xv.z, w2.x, acc.x);
            acc.y = fmaf(xv.z, w2.y, acc.y);
            acc.z = fmaf(xv.z, w2.z, acc.z);
            acc.w = fmaf(xv.z, w2.w, acc.w);
            acc.x = fmaf(xv.w, w3.x, acc.x);
            acc.y = fmaf(xv.w, w3.y, acc.y);
            acc.z = fmaf(xv.w, w3.z, acc.z);
            acc.w = fmaf(xv.w, w3.w, acc.w);
        }
    }

    const float qs = 0.44721359549995793f;          // 1/sqrt(5)
    const int tok = tok0 + tl;
    const int b   = tok >> 11;
    const int n   = tok & (NN-1);
    const float av[4] = {acc.x, acc.y, acc.z, acc.w};
    #pragma unroll
    for (int i=0;i<4;i++){
        const int c = r*4 + i;
        if (c >= 30) continue;
        const int mat = c / 10;
        const int d10 = c - mat*10;
        const int h   = d10 / 5;
        const int dd  = d10 - h*5;
        float v = av[i] + ((mat==0) ? bq[d10] : (mat==1) ? bk[d10] : bv[d10]);
        if (mat==0) v *= qs;
        qkv[(size_t)mat*BH*NN*8 + (((size_t)(b*NHD+h))*NN + n)*8 + dd] = v;
    }
}

// ---------------------------------------------------------------- kernel 2
// grid (qt=32, kc=8, bh=32), block 64. One q-row per lane, wave-uniform k.
// scores = sin(q.k/sqrt5) are in [-1,1] -> exp(sin) needs no max pass.
__global__ __launch_bounds__(64) void attn_kernel(
    const float* __restrict__ qkv, float* __restrict__ part)
{
    const int qt   = blockIdx.x;
    const int kc   = blockIdx.y;
    const int bh   = blockIdx.z;
    const int lane = threadIdx.x;
    const int qtile0 = qt*64;
    const int k0     = kc*KC;
    if (k0 > qtile0 + 63) return;          // uniform early-out (causal)

    const int q = qtile0 + lane;
    const float* qr = qkv + ((size_t)bh*NN + q)*8;
    const float4 qv = *(const float4*)qr;
    const float  q4 = qr[4];

    const float* kbase = qkv + (size_t)BH*NN*8 + (size_t)bh*NN*8;
    const float* vbase = kbase + (size_t)BH*NN*8;
    const int kend = (k0+KC < qtile0+64) ? (k0+KC) : (qtile0+64);  // uniform

    float denom=0.f, a0=0.f, a1=0.f, a2=0.f, a3=0.f, a4=0.f;
    #pragma unroll 4
    for (int k=k0; k<kend; ++k){
        const float* kr = kbase + (size_t)k*8;   // wave-uniform
        const float* vr = vbase + (size_t)k*8;
        float s = qv.x*kr[0] + qv.y*kr[1] + qv.z*kr[2] + qv.w*kr[3] + q4*kr[4];
        float e = __expf(__sinf(s));
        e = (k <= q) ? e : 0.f;                  // causal mask, per-lane
        denom += e;
        a0 = fmaf(e, vr[0], a0);
        a1 = fmaf(e, vr[1], a1);
        a2 = fmaf(e, vr[2], a2);
        a3 = fmaf(e, vr[3], a3);
        a4 = fmaf(e, vr[4], a4);
    }
    float* pr = part + (((size_t)kc*BH + bh)*NN + q)*8;
    *(float4*)pr = make_float4(a0,a1,a2,a3);
    pr[4] = a4;
    pr[5] = denom;
}

// ---------------------------------------------------------------- kernel 3a
// One TOKEN PER LANE: part-reduce + Wm1 + leaky_relu, write h1[tok][20].
// This de-replicates the 64x-redundant per-lane h1 math R3's mlp_kernel had.
__global__ __launch_bounds__(256) void h1_kernel(
    const float* __restrict__ part,
    const float* __restrict__ Wm1, const float* __restrict__ bm1,
    float* __restrict__ h1buf)
{
    const int tok = blockIdx.x*256 + threadIdx.x;   // 0..32767
    const int b   = tok >> 11;
    const int n   = tok & (NN-1);
    const int nc  = (n >> 8) + 1;                   // valid causal k-chunks

    float vals[DKK];
    #pragma unroll
    for (int h=0;h<NHD;h++){
        const int bh = b*NHD + h;
        float s0=0,s1=0,s2=0,s3=0,s4=0,sd=0;
        for (int c=0;c<nc;c++){
            const float* pr = part + (((size_t)c*BH + bh)*NN + n)*8;  // coalesced
            const float4 p0 = *(const float4*)pr;
            const float4 p1 = *(const float4*)(pr+4);
            s0+=p0.x; s1+=p0.y; s2+=p0.z; s3+=p0.w; s4+=p1.x; sd+=p1.y;
        }
        const float inv = 1.0f / sd;
        vals[h*DH+0]=s0*inv; vals[h*DH+1]=s1*inv; vals[h*DH+2]=s2*inv;
        vals[h*DH+3]=s3*inv; vals[h*DH+4]=s4*inv;
    }

    float h1[HID];
    #pragma unroll
    for (int jo=0;jo<HID;jo++){
        float t = bm1[jo];
        #pragma unroll
        for (int d=0;d<DKK;d++) t = fmaf(vals[d], Wm1[d*HID+jo], t);
        h1[jo] = (t > 0.f) ? t : 0.01f*t;
    }
    float* hr = h1buf + (size_t)tok*HID;            // 80B rows, 16B-aligned
    #pragma unroll
    for (int j5=0;j5<5;j5++)
        *(float4*)(hr + j5*4) = make_float4(h1[j5*4+0],h1[j5*4+1],h1[j5*4+2],h1[j5*4+3]);
}

// ---------------------------------------------------------------- kernel 3b
// One wave = half an output row (256 cols, 4/lane) for 8 tokens; Wm2 slice
// in registers; per token: 20 uniform h1 loads + 80 FMA + dwordx4 store.
__global__ __launch_bounds__(256) void out_kernel(
    const float* __restrict__ h1buf,
    const float* __restrict__ Wm2, const float* __restrict__ bm2,
    float* __restrict__ out)
{
    const int wave = threadIdx.x >> 6;
    const int lane = threadIdx.x & 63;
    const int unit = blockIdx.x*4 + wave;   // 0..8191
    const int hc   = unit & 1;
    const int tg   = unit >> 1;
    const int o0   = hc*256 + lane*4;

    float4 w2[HID];
    #pragma unroll
    for (int j=0;j<HID;j++) w2[j] = *(const float4*)(Wm2 + j*DOUT + o0);
    const float4 b2 = *(const float4*)(bm2 + o0);

    for (int ti=0; ti<8; ++ti){
        const int tok = tg*8 + ti;
        const float* hr = h1buf + (size_t)tok*HID;  // wave-uniform
        float4 acc = b2;
        #pragma unroll
        for (int j5=0;j5<5;j5++){
            const float4 hv = *(const float4*)(hr + j5*4);
            const float h0=hv.x, h1v=hv.y, h2=hv.z, h3=hv.w;
            acc.x = fmaf(h0, w2[j5*4+0].x, acc.x);
            acc.y = fmaf(h0, w2[j5*4+0].y, acc.y);
            acc.z = fmaf(h0, w2[j5*4+0].z, acc.z);
            acc.w = fmaf(h0, w2[j5*4+0].w, acc.w);
            acc.x = fmaf(h1v, w2[j5*4+1].x, acc.x);
            acc.y = fmaf(h1v, w2[j5*4+1].y, acc.y);
            acc.z = fmaf(h1v, w2[j5*4+1].z, acc.z);
            acc.w = fmaf(h1v, w2[j5*4+1].w, acc.w);
            acc.x = fmaf(h2, w2[j5*4+2].x, acc.x);
            acc.y = fmaf(h2, w2[j5*4+2].y, acc.y);
            acc.z = fmaf(h2, w2[j5*4+2].z, acc.z);
            acc.w = fmaf(h2, w2[j5*4+2].w, acc.w);
            acc.x = fmaf(h3, w2[j5*4+3].x, acc.x);
            acc.y = fmaf(h3, w2[j5*4+3].y, acc.y);
            acc.z = fmaf(h3, w2[j5*4+3].z, acc.z);
            acc.w = fmaf(h3, w2[j5*4+3].w, acc.w);
        }
        *(float4*)(out + (size_t)tok*DOUT + o0) = acc;
    }
}

// ---------------------------------------------------------------- launch
extern "C" void kernel_launch(void* const* d_in, const int* in_sizes, int n_in,
                              void* d_out, int out_size, void* d_ws, size_t ws_size,
                              hipStream_t stream) {
    const float* x   = (const float*)d_in[0];
    const float* Wq  = (const float*)d_in[1];
    const float* bq  = (const float*)d_in[2];
    const float* Wk  = (const float*)d_in[3];
    const float* bk  = (const float*)d_in[4];
    const float* Wv  = (const float*)d_in[5];
    const float* bv  = (const float*)d_in[6];
    const float* Wm1 = (const float*)d_in[7];
    const float* bm1 = (const float*)d_in[8];
    const float* Wm2 = (const float*)d_in[9];
    const float* bm2 = (const float*)d_in[10];
    float* out = (float*)d_out;

    float* qkv   = (float*)d_ws;
    float* part  = qkv + QKV_ELEMS;
    float* Wpack = part + PART_ELEMS;
    float* h1buf = qkv;   // overlays qkv: dead after attn_kernel (stream-ordered)

    pack_w_kernel<<<dim3(64), dim3(256), 0, stream>>>(Wq, Wk, Wv, Wpack);
    proj_kernel<<<dim3(1024), dim3(256), 0, stream>>>(x, Wpack, bq, bk, bv, qkv);
    attn_kernel<<<dim3(32, NKC, BH), dim3(64), 0, stream>>>(qkv, part);
    h1_kernel<<<dim3(128), dim3(256), 0, stream>>>(part, Wm1, bm1, h1buf);
    out_kernel<<<dim3(2048), dim3(256), 0, stream>>>(h1buf, Wm2, bm2, out);
}